// Round 1
// baseline (5554.771 us; speedup 1.0000x reference)
//
#include <hip/hip_runtime.h>
#include <math.h>

// Problem constants
#define NB   64      // batch
#define NN   400     // nodes / seq len
#define DD   256     // model dim
#define NHH  4       // heads
#define HDD  64      // head dim
#define MROWS (NB*NN)   // 25600

#define BM 64
#define BN 64
#define BK 16

// ---------------------------------------------------------------------------
// Generic NT GEMM: C[m,n] = (sum_k A[m,k]*W[n,k] + bias[n]) * rowscale[m], opt relu
// M % 64 == 0, Nout % 64 == 0, K % 16 == 0 (all call sites satisfy this)
// ---------------------------------------------------------------------------
__global__ __launch_bounds__(256) void gemm_nt(
    const float* __restrict__ A, int lda,
    const float* __restrict__ W, int ldw,
    const float* __restrict__ bias,
    const float* __restrict__ rowscale,
    float* __restrict__ C, int ldc,
    int M, int Nout, int K, int relu)
{
    __shared__ float As[BK][BM + 1];
    __shared__ float Ws[BK][BN + 1];
    const int tid = threadIdx.x;
    const int m0 = blockIdx.y * BM;
    const int n0 = blockIdx.x * BN;
    const int ty = tid >> 4, tx = tid & 15;
    const int lk = tid & 15, lr = tid >> 4;
    float acc[4][4] = {};

    for (int k0 = 0; k0 < K; k0 += BK) {
#pragma unroll
        for (int i = 0; i < 4; ++i) {
            int r = lr + 16 * i;
            As[lk][r] = A[(size_t)(m0 + r) * lda + k0 + lk];
            Ws[lk][r] = W[(size_t)(n0 + r) * ldw + k0 + lk];
        }
        __syncthreads();
#pragma unroll
        for (int kk = 0; kk < BK; ++kk) {
            float a[4], b[4];
#pragma unroll
            for (int i = 0; i < 4; ++i) a[i] = As[kk][ty * 4 + i];
#pragma unroll
            for (int j = 0; j < 4; ++j) b[j] = Ws[kk][tx * 4 + j];
#pragma unroll
            for (int i = 0; i < 4; ++i)
#pragma unroll
                for (int j = 0; j < 4; ++j)
                    acc[i][j] = fmaf(a[i], b[j], acc[i][j]);
        }
        __syncthreads();
    }
#pragma unroll
    for (int i = 0; i < 4; ++i) {
        int m = m0 + ty * 4 + i;
        float rs = rowscale ? rowscale[m] : 1.0f;
#pragma unroll
        for (int j = 0; j < 4; ++j) {
            int n = n0 + tx * 4 + j;
            float v = acc[i][j];
            if (bias) v += bias[n];
            v *= rs;
            if (relu) v = fmaxf(v, 0.0f);
            C[(size_t)m * ldc + n] = v;
        }
    }
}

// ---------------------------------------------------------------------------
// Batched TN GEMM for GCN aggregation:
// C[b,j,d] = relu?( dinv[b,j] * sum_i Adj[b,i,j] * X[b,i,d] + bias[d] )
// ---------------------------------------------------------------------------
__global__ __launch_bounds__(256) void gemm_tn_gcn(
    const float* __restrict__ Adj,   // [B,NN,NN]
    const float* __restrict__ X,     // [B,NN,DD]
    const float* __restrict__ dinv,  // [B*NN]
    const float* __restrict__ bias,  // [DD]
    float* __restrict__ C,           // [B,NN,DD]
    int relu)
{
    __shared__ float As[BK][BM + 1];  // As[kk][j]
    __shared__ float Xs[BK][BN + 1];  // Xs[kk][d]
    const int b = blockIdx.z;
    const int j0 = blockIdx.y * BM;
    const int d0 = blockIdx.x * BN;
    const int tid = threadIdx.x;
    const int ty = tid >> 4, tx = tid & 15;
    const int lc = tid & 63, lkk = tid >> 6;
    const float* Ab = Adj + (size_t)b * NN * NN;
    const float* Xb = X + (size_t)b * NN * DD;
    float acc[4][4] = {};

    for (int k0 = 0; k0 < NN; k0 += BK) {
#pragma unroll
        for (int i = 0; i < 4; ++i) {
            int kk = lkk + 4 * i;
            int jj = j0 + lc;
            As[kk][lc] = (jj < NN) ? Ab[(size_t)(k0 + kk) * NN + jj] : 0.0f;
            Xs[kk][lc] = Xb[(size_t)(k0 + kk) * DD + d0 + lc];
        }
        __syncthreads();
#pragma unroll
        for (int kk = 0; kk < BK; ++kk) {
            float a[4], x[4];
#pragma unroll
            for (int i = 0; i < 4; ++i) a[i] = As[kk][ty * 4 + i];
#pragma unroll
            for (int j = 0; j < 4; ++j) x[j] = Xs[kk][tx * 4 + j];
#pragma unroll
            for (int i = 0; i < 4; ++i)
#pragma unroll
                for (int j = 0; j < 4; ++j)
                    acc[i][j] = fmaf(a[i], x[j], acc[i][j]);
        }
        __syncthreads();
    }
#pragma unroll
    for (int i = 0; i < 4; ++i) {
        int j = j0 + ty * 4 + i;
        if (j >= NN) continue;
        float s = dinv[b * NN + j];
#pragma unroll
        for (int jj = 0; jj < 4; ++jj) {
            int d = d0 + tx * 4 + jj;
            float v = acc[i][jj] * s + bias[d];
            if (relu) v = fmaxf(v, 0.0f);
            C[((size_t)b * NN + j) * DD + d] = v;
        }
    }
}

// ---------------------------------------------------------------------------
// Column sums of sc -> dinv[b,j] = 1/sqrt(sum_i sc[b,i,j])
// ---------------------------------------------------------------------------
__global__ void colsum_dinv(const float* __restrict__ sc, float* __restrict__ dinv)
{
    int b = blockIdx.y;
    int j = blockIdx.x * 256 + threadIdx.x;
    if (j >= NN) return;
    const float* p = sc + (size_t)b * NN * NN + j;
    float s = 0.0f;
    for (int i = 0; i < NN; ++i) s += p[(size_t)i * NN];
    dinv[b * NN + j] = (s > 0.0f) ? 1.0f / sqrtf(s) : 0.0f;
}

// ---------------------------------------------------------------------------
// Attention: one block per (q-tile of 32 rows, head, batch).
// Q/K/V at ptr[(b*NN+n)*ld + h*64 + d]; out[(b*NN+n)*ldo + h*64 + d]
// ---------------------------------------------------------------------------
#define TQ 32
#define TK 64
__global__ __launch_bounds__(256) void attn_kernel(
    const float* __restrict__ Qp, const float* __restrict__ Kp,
    const float* __restrict__ Vp, int ld,
    float* __restrict__ Out, int ldo)
{
    __shared__ float S[TQ][401];
    __shared__ float Qs[TQ][65];
    __shared__ float KVs[TK][65];
    __shared__ float red[TQ][8];
    __shared__ float rowmax[TQ], rowsum[TQ];

    const int qt = blockIdx.x, h = blockIdx.y, b = blockIdx.z;
    const int tid = threadIdx.x;
    const size_t base = (size_t)b * NN * ld + h * HDD;

    // zero S (covers the k>=400 tail read harmlessly)
    for (int idx = tid; idx < TQ * 401; idx += 256) (&S[0][0])[idx] = 0.0f;

    // load Q tile
    for (int idx = tid; idx < TQ * HDD; idx += 256) {
        int r = idx >> 6, d = idx & 63;
        int n = qt * TQ + r;
        Qs[r][d] = (n < NN) ? Qp[base + (size_t)n * ld + d] : 0.0f;
    }
    __syncthreads();

    const int ty = tid >> 4, tx = tid & 15;
    const int q0 = ty * 2;

    // phase 1: S = Q K^T / 8
    for (int kt = 0; kt < NN; kt += TK) {
        for (int idx = tid; idx < TK * HDD; idx += 256) {
            int r = idx >> 6, d = idx & 63;
            int n = kt + r;
            KVs[r][d] = (n < NN) ? Kp[base + (size_t)n * ld + d] : 0.0f;
        }
        __syncthreads();
        float acc[2][4] = {};
        const int k0 = tx * 4;
#pragma unroll 8
        for (int d = 0; d < HDD; ++d) {
            float a0 = Qs[q0][d], a1 = Qs[q0 + 1][d];
#pragma unroll
            for (int j = 0; j < 4; ++j) {
                float bb = KVs[k0 + j][d];
                acc[0][j] = fmaf(a0, bb, acc[0][j]);
                acc[1][j] = fmaf(a1, bb, acc[1][j]);
            }
        }
#pragma unroll
        for (int i = 0; i < 2; ++i)
#pragma unroll
            for (int j = 0; j < 4; ++j) {
                int k = kt + k0 + j;
                if (k < NN) S[q0 + i][k] = acc[i][j] * 0.125f;
            }
        __syncthreads();
    }

    // softmax rows (unnormalized exp, keep row sums)
    {
        const int rrow = tid >> 3, sub = tid & 7;
        float pm = -1e30f;
        for (int k = sub; k < NN; k += 8) pm = fmaxf(pm, S[rrow][k]);
        red[rrow][sub] = pm;
        __syncthreads();
        if (sub == 0) {
            float m = red[rrow][0];
            for (int t = 1; t < 8; ++t) m = fmaxf(m, red[rrow][t]);
            rowmax[rrow] = m;
        }
        __syncthreads();
        float rm = rowmax[rrow];
        float ps = 0.0f;
        for (int k = sub; k < NN; k += 8) {
            float e = __expf(S[rrow][k] - rm);
            S[rrow][k] = e;
            ps += e;
        }
        red[rrow][sub] = ps;
        __syncthreads();
        if (sub == 0) {
            float s2 = 0.0f;
            for (int t = 0; t < 8; ++t) s2 += red[rrow][t];
            rowsum[rrow] = s2;
        }
        __syncthreads();
    }

    // phase 2: O = P V
    float o[2][4] = {};
    const int d0 = tx * 4;
    for (int vt = 0; vt < NN; vt += TK) {
        for (int idx = tid; idx < TK * HDD; idx += 256) {
            int r = idx >> 6, d = idx & 63;
            int n = vt + r;
            KVs[r][d] = (n < NN) ? Vp[base + (size_t)n * ld + d] : 0.0f;
        }
        __syncthreads();
        int klim = NN - vt; if (klim > TK) klim = TK;
        for (int kk = 0; kk < klim; ++kk) {
            float p0 = S[q0][vt + kk], p1 = S[q0 + 1][vt + kk];
#pragma unroll
            for (int j = 0; j < 4; ++j) {
                float vv = KVs[kk][d0 + j];
                o[0][j] = fmaf(p0, vv, o[0][j]);
                o[1][j] = fmaf(p1, vv, o[1][j]);
            }
        }
        __syncthreads();
    }
#pragma unroll
    for (int i = 0; i < 2; ++i) {
        int q = qt * TQ + q0 + i;
        if (q >= NN) continue;
        float inv = 1.0f / rowsum[q0 + i];
#pragma unroll
        for (int j = 0; j < 4; ++j)
            Out[((size_t)b * NN + q) * ldo + h * HDD + d0 + j] = o[i][j] * inv;
    }
}

// ---------------------------------------------------------------------------
// Fused residual + LayerNorm: y = LN(x + a) * g + b   (row len 256)
// ---------------------------------------------------------------------------
__global__ __launch_bounds__(256) void ln_res(
    const float* __restrict__ x, const float* __restrict__ a,
    const float* __restrict__ g, const float* __restrict__ bb,
    float* __restrict__ y, int rows)
{
    const int wave = threadIdx.x >> 6;
    const int lane = threadIdx.x & 63;
    const int row = blockIdx.x * 4 + wave;
    if (row >= rows) return;
    float4 xv = ((const float4*)(x + (size_t)row * DD))[lane];
    float4 av = ((const float4*)(a + (size_t)row * DD))[lane];
    float4 v;
    v.x = xv.x + av.x; v.y = xv.y + av.y; v.z = xv.z + av.z; v.w = xv.w + av.w;
    float s = v.x + v.y + v.z + v.w;
#pragma unroll
    for (int off = 32; off >= 1; off >>= 1) s += __shfl_xor(s, off);
    float mu = s * (1.0f / 256.0f);
    float d0 = v.x - mu, d1 = v.y - mu, d2 = v.z - mu, d3 = v.w - mu;
    float ss = d0 * d0 + d1 * d1 + d2 * d2 + d3 * d3;
#pragma unroll
    for (int off = 32; off >= 1; off >>= 1) ss += __shfl_xor(ss, off);
    float rstd = 1.0f / sqrtf(ss * (1.0f / 256.0f) + 1e-5f);
    float4 gv = ((const float4*)g)[lane];
    float4 bv = ((const float4*)bb)[lane];
    float4 out;
    out.x = d0 * rstd * gv.x + bv.x;
    out.y = d1 * rstd * gv.y + bv.y;
    out.z = d2 * rstd * gv.z + bv.z;
    out.w = d3 * rstd * gv.w + bv.w;
    ((float4*)(y + (size_t)row * DD))[lane] = out;
}

// ---------------------------------------------------------------------------
// Classifier split-K: acc[b,o] += sum over K-chunk of 0.5*(C1+C2)[b,k]*W1[o,k]
// grid: (Nout/64=2, 102400/512=200)
// ---------------------------------------------------------------------------
#define CKC 512
__global__ __launch_bounds__(256) void cls_splitk(
    const float* __restrict__ C1, const float* __restrict__ C2,
    const float* __restrict__ W1, float* __restrict__ accum)
{
    __shared__ float As[BK][BM + 1];
    __shared__ float Ws[BK][BN + 1];
    const int n0 = blockIdx.x * 64;
    const int k0 = blockIdx.y * CKC;
    const int tid = threadIdx.x;
    const int ty = tid >> 4, tx = tid & 15;
    const int lk = tid & 15, lr = tid >> 4;
    float acc[4][4] = {};
    for (int kc = 0; kc < CKC; kc += BK) {
        int kb = k0 + kc;
#pragma unroll
        for (int i = 0; i < 4; ++i) {
            int r = lr + 16 * i;
            As[lk][r] = 0.5f * (C1[(size_t)r * 102400 + kb + lk] +
                                C2[(size_t)r * 102400 + kb + lk]);
            Ws[lk][r] = W1[(size_t)(n0 + r) * 102400 + kb + lk];
        }
        __syncthreads();
#pragma unroll
        for (int kk = 0; kk < BK; ++kk) {
            float a[4], b[4];
#pragma unroll
            for (int i = 0; i < 4; ++i) a[i] = As[kk][ty * 4 + i];
#pragma unroll
            for (int j = 0; j < 4; ++j) b[j] = Ws[kk][tx * 4 + j];
#pragma unroll
            for (int i = 0; i < 4; ++i)
#pragma unroll
                for (int j = 0; j < 4; ++j)
                    acc[i][j] = fmaf(a[i], b[j], acc[i][j]);
        }
        __syncthreads();
    }
#pragma unroll
    for (int i = 0; i < 4; ++i)
#pragma unroll
        for (int j = 0; j < 4; ++j)
            atomicAdd(&accum[(ty * 4 + i) * 128 + n0 + tx * 4 + j], acc[i][j]);
}

__global__ void zero_buf(float* p, int n)
{
    int i = blockIdx.x * 256 + threadIdx.x;
    if (i < n) p[i] = 0.0f;
}

__global__ void logits_final(
    const float* __restrict__ clsh, const float* __restrict__ b1,
    const float* __restrict__ w2, const float* __restrict__ b2,
    float* __restrict__ out)
{
    __shared__ float t[128];
    int b = blockIdx.x;
    int tid = threadIdx.x;
    t[tid] = fmaxf(clsh[b * 128 + tid] + b1[tid], 0.0f);
    __syncthreads();
    if (tid < 2) {
        float s = b2[tid];
        for (int o = 0; o < 128; ++o) s += t[o] * w2[tid * 128 + o];
        out[b * 2 + tid] = s;
    }
}

// ---------------------------------------------------------------------------
extern "C" void kernel_launch(void* const* d_in, const int* in_sizes, int n_in,
                              void* d_out, int out_size, void* d_ws, size_t ws_size,
                              hipStream_t stream)
{
    const float* fc        = (const float*)d_in[0];
    const float* sc        = (const float*)d_in[1];
    const float* proj_w    = (const float*)d_in[2];
    const float* proj_b    = (const float*)d_in[3];
    const float* enc_qkv_w = (const float*)d_in[4];
    const float* enc_qkv_b = (const float*)d_in[5];
    const float* enc_out_w = (const float*)d_in[6];
    const float* enc_out_b = (const float*)d_in[7];
    const float* enc_l1_w  = (const float*)d_in[8];
    const float* enc_l1_b  = (const float*)d_in[9];
    const float* enc_l2_w  = (const float*)d_in[10];
    const float* enc_l2_b  = (const float*)d_in[11];
    const float* enc_n1_g  = (const float*)d_in[12];
    const float* enc_n1_b  = (const float*)d_in[13];
    const float* enc_n2_g  = (const float*)d_in[14];
    const float* enc_n2_b  = (const float*)d_in[15];
    const float* gcn_w1    = (const float*)d_in[16];
    const float* gcn_b1    = (const float*)d_in[17];
    const float* gcn_w2    = (const float*)d_in[18];
    const float* gcn_b2    = (const float*)d_in[19];
    const float* ca1_qkv_w = (const float*)d_in[20];
    const float* ca1_qkv_b = (const float*)d_in[21];
    const float* ca1_out_w = (const float*)d_in[22];
    const float* ca1_out_b = (const float*)d_in[23];
    const float* ca1_n_g   = (const float*)d_in[24];
    const float* ca1_n_b   = (const float*)d_in[25];
    const float* ca2_qkv_w = (const float*)d_in[26];
    const float* ca2_qkv_b = (const float*)d_in[27];
    const float* ca2_out_w = (const float*)d_in[28];
    const float* ca2_out_b = (const float*)d_in[29];
    const float* ca2_n_g   = (const float*)d_in[30];
    const float* ca2_n_b   = (const float*)d_in[31];
    const float* cls_w1    = (const float*)d_in[32];
    const float* cls_b1    = (const float*)d_in[33];
    const float* cls_w2    = (const float*)d_in[34];
    const float* cls_b2    = (const float*)d_in[35];

    float* p = (float*)d_ws;
    float* bufH  = p; p += (size_t)MROWS * DD;       // Z_F working
    float* bufA  = p; p += (size_t)MROWS * DD;
    float* bufB  = p; p += (size_t)MROWS * DD;
    float* bufC  = p; p += (size_t)MROWS * DD;       // Z_F_cross
    float* bufZS = p; p += (size_t)MROWS * DD;       // Z_S / Z_S_cross
    float* bufBig = p; p += (size_t)MROWS * 1024;    // QKV (768) / FF (1024)
    float* dinv  = p; p += MROWS;
    float* clsh  = p; p += NB * 128;

    const int M = MROWS;
    dim3 blk(256);

    // ---- FC branch: input projection ----
    gemm_nt<<<dim3(4, 400), blk, 0, stream>>>(fc, NN, proj_w, NN, proj_b, nullptr,
                                              bufH, DD, M, DD, NN, 0);
    // ---- 2 encoder layers ----
    for (int l = 0; l < 2; ++l) {
        gemm_nt<<<dim3(12, 400), blk, 0, stream>>>(
            bufH, DD, enc_qkv_w + (size_t)l * 768 * DD, DD, enc_qkv_b + l * 768,
            nullptr, bufBig, 768, M, 768, DD, 0);
        attn_kernel<<<dim3(13, NHH, NB), blk, 0, stream>>>(
            bufBig, bufBig + 256, bufBig + 512, 768, bufA, DD);
        gemm_nt<<<dim3(4, 400), blk, 0, stream>>>(
            bufA, DD, enc_out_w + (size_t)l * DD * DD, DD, enc_out_b + l * DD,
            nullptr, bufB, DD, M, DD, DD, 0);
        ln_res<<<6400, blk, 0, stream>>>(bufH, bufB, enc_n1_g + l * DD,
                                         enc_n1_b + l * DD, bufH, M);
        gemm_nt<<<dim3(16, 400), blk, 0, stream>>>(
            bufH, DD, enc_l1_w + (size_t)l * 1024 * DD, DD, enc_l1_b + l * 1024,
            nullptr, bufBig, 1024, M, 1024, DD, 1);
        gemm_nt<<<dim3(4, 400), blk, 0, stream>>>(
            bufBig, 1024, enc_l2_w + (size_t)l * DD * 1024, 1024, enc_l2_b + l * DD,
            nullptr, bufA, DD, M, DD, 1024, 0);
        ln_res<<<6400, blk, 0, stream>>>(bufH, bufA, enc_n2_g + l * DD,
                                         enc_n2_b + l * DD, bufH, M);
    }
    // ---- GCN branch ----
    colsum_dinv<<<dim3(2, NB), blk, 0, stream>>>(sc, dinv);
    gemm_nt<<<dim3(4, 400), blk, 0, stream>>>(sc, NN, gcn_w1, NN, nullptr, dinv,
                                              bufA, DD, M, DD, NN, 0);
    gemm_tn_gcn<<<dim3(4, 7, NB), blk, 0, stream>>>(sc, bufA, dinv, gcn_b1, bufB, 1);
    gemm_nt<<<dim3(4, 400), blk, 0, stream>>>(bufB, DD, gcn_w2, DD, nullptr, dinv,
                                              bufA, DD, M, DD, DD, 0);
    gemm_tn_gcn<<<dim3(4, 7, NB), blk, 0, stream>>>(sc, bufA, dinv, gcn_b2, bufZS, 0);

    // ---- Cross attention 1: Q = Z_F, KV = Z_S ----
    gemm_nt<<<dim3(4, 400), blk, 0, stream>>>(bufH, DD, ca1_qkv_w, DD, ca1_qkv_b,
                                              nullptr, bufBig, 768, M, 256, DD, 0);
    gemm_nt<<<dim3(8, 400), blk, 0, stream>>>(bufZS, DD, ca1_qkv_w + 256 * DD, DD,
                                              ca1_qkv_b + 256, nullptr,
                                              bufBig + 256, 768, M, 512, DD, 0);
    attn_kernel<<<dim3(13, NHH, NB), blk, 0, stream>>>(
        bufBig, bufBig + 256, bufBig + 512, 768, bufA, DD);
    gemm_nt<<<dim3(4, 400), blk, 0, stream>>>(bufA, DD, ca1_out_w, DD, ca1_out_b,
                                              nullptr, bufB, DD, M, DD, DD, 0);
    ln_res<<<6400, blk, 0, stream>>>(bufH, bufB, ca1_n_g, ca1_n_b, bufC, M);

    // ---- Cross attention 2: Q = Z_S, KV = Z_F ----
    gemm_nt<<<dim3(4, 400), blk, 0, stream>>>(bufZS, DD, ca2_qkv_w, DD, ca2_qkv_b,
                                              nullptr, bufBig, 768, M, 256, DD, 0);
    gemm_nt<<<dim3(8, 400), blk, 0, stream>>>(bufH, DD, ca2_qkv_w + 256 * DD, DD,
                                              ca2_qkv_b + 256, nullptr,
                                              bufBig + 256, 768, M, 512, DD, 0);
    attn_kernel<<<dim3(13, NHH, NB), blk, 0, stream>>>(
        bufBig, bufBig + 256, bufBig + 512, 768, bufA, DD);
    gemm_nt<<<dim3(4, 400), blk, 0, stream>>>(bufA, DD, ca2_out_w, DD, ca2_out_b,
                                              nullptr, bufB, DD, M, DD, DD, 0);
    ln_res<<<6400, blk, 0, stream>>>(bufZS, bufB, ca2_n_g, ca2_n_b, bufZS, M);

    // ---- Classifier ----
    zero_buf<<<(NB * 128 + 255) / 256, blk, 0, stream>>>(clsh, NB * 128);
    cls_splitk<<<dim3(2, 200), blk, 0, stream>>>(bufC, bufZS, cls_w1, clsh);
    logits_final<<<NB, 128, 0, stream>>>(clsh, cls_b1, cls_w2, cls_b2, (float*)d_out);
}

// Round 2
// 1927.821 us; speedup vs baseline: 2.8814x; 2.8814x over previous
//
#include <hip/hip_runtime.h>
#include <math.h>

// Problem constants
#define NB   64      // batch
#define NN   400     // nodes / seq len
#define DD   256     // model dim
#define NHH  4       // heads
#define HDD  64      // head dim
#define MROWS (NB*NN)   // 25600

typedef __attribute__((ext_vector_type(8))) short bf16x8;
typedef __attribute__((ext_vector_type(4))) float f32x4;

__device__ __forceinline__ short f2bf(float x) {
    union { float f; unsigned u; } v; v.f = x;
    return (short)((v.u + 0x7FFFu + ((v.u >> 16) & 1u)) >> 16);
}

#define GF_RELU 1
#define GF_AT   2
#define GF_BT   4

// ---------------------------------------------------------------------------
// Unified bf16-MFMA GEMM, 128x128 tile, BK=32, 4 waves x (4x4) 16x16x32 MFMAs.
// C[z][m][n] = act( rowscale[z][m] * sum_k Aacc(m,k)*Bacc(k,n) + bias[n] )
//   aT=0: Aacc(m,k) = A[z*sA + m*lda + k]     (k-contiguous rows)
//   aT=1: Aacc(m,k) = A[z*sA + k*lda + m]     (k-strided; Adj^T case)
//   bT=0: Bacc(k,n) = B[z*sB + n*ldb + k]     (weights W[n][k])
//   bT=1: Bacc(k,n) = B[z*sB + k*ldb + n]     (X[k][n]; k-strided)
// LDS fragment layout: L[(kq*128 + mn)*8 + j] holds element (mn, k=kq*8+j).
// ---------------------------------------------------------------------------
__global__ __launch_bounds__(256) void gemm_mfma(
    const float* __restrict__ A, int lda, long long sA,
    const float* __restrict__ Bm, int ldb, long long sB,
    const float* __restrict__ bias,
    const float* __restrict__ rowscale, int sRS,
    float* __restrict__ C, int ldc, long long sC,
    int M, int N, int K, int flags)
{
    __shared__ short Al[4 * 128 * 8];
    __shared__ short Bl[4 * 128 * 8];
    const int tid = threadIdx.x;
    const int z = blockIdx.z;
    const int m0 = blockIdx.y * 128, n0 = blockIdx.x * 128;
    const float* Ab = A + (size_t)z * sA;
    const float* Bb = Bm + (size_t)z * sB;
    float* Cb = C + (size_t)z * sC;

    const int w = tid >> 6, lane = tid & 63;
    const int quad = lane >> 4, l15 = lane & 15;
    const int wm = w & 1, wn = w >> 1;

    f32x4 acc[4][4] = {};

    const int KT = (K + 31) >> 5;
    for (int kt = 0; kt < KT; ++kt) {
        const int k0 = kt << 5;
        // ---- stage A ----
        if (!(flags & GF_AT)) {
            for (int t = tid; t < 512; t += 256) {
                int m = t >> 2, q = t & 3;
                int row = m0 + m, kk = k0 + q * 8;
                bf16x8 s8;
                if (row < M && kk < K) {
                    const float* src = Ab + (size_t)row * lda + kk;
                    float4 v0 = *(const float4*)src;
                    float4 v1 = *(const float4*)(src + 4);
                    s8[0] = f2bf(v0.x); s8[1] = f2bf(v0.y); s8[2] = f2bf(v0.z); s8[3] = f2bf(v0.w);
                    s8[4] = f2bf(v1.x); s8[5] = f2bf(v1.y); s8[6] = f2bf(v1.z); s8[7] = f2bf(v1.w);
                } else {
                    for (int j = 0; j < 8; ++j) s8[j] = 0;
                }
                *reinterpret_cast<bf16x8*>(&Al[(q * 128 + m) * 8]) = s8;
            }
        } else {
            for (int t = tid; t < 512; t += 256) {
                int c = t & 127, q = t >> 7;
                int m = m0 + c;
                bf16x8 s8;
#pragma unroll
                for (int i = 0; i < 8; ++i) {
                    int k = k0 + q * 8 + i;
                    float v = (m < M && k < K) ? Ab[(size_t)k * lda + m] : 0.0f;
                    s8[i] = f2bf(v);
                }
                *reinterpret_cast<bf16x8*>(&Al[(q * 128 + c) * 8]) = s8;
            }
        }
        // ---- stage B ----
        if (!(flags & GF_BT)) {
            for (int t = tid; t < 512; t += 256) {
                int n = t >> 2, q = t & 3;
                int row = n0 + n, kk = k0 + q * 8;
                bf16x8 s8;
                if (row < N && kk < K) {
                    const float* src = Bb + (size_t)row * ldb + kk;
                    float4 v0 = *(const float4*)src;
                    float4 v1 = *(const float4*)(src + 4);
                    s8[0] = f2bf(v0.x); s8[1] = f2bf(v0.y); s8[2] = f2bf(v0.z); s8[3] = f2bf(v0.w);
                    s8[4] = f2bf(v1.x); s8[5] = f2bf(v1.y); s8[6] = f2bf(v1.z); s8[7] = f2bf(v1.w);
                } else {
                    for (int j = 0; j < 8; ++j) s8[j] = 0;
                }
                *reinterpret_cast<bf16x8*>(&Bl[(q * 128 + n) * 8]) = s8;
            }
        } else {
            for (int t = tid; t < 512; t += 256) {
                int c = t & 127, q = t >> 7;
                int n = n0 + c;
                bf16x8 s8;
#pragma unroll
                for (int i = 0; i < 8; ++i) {
                    int k = k0 + q * 8 + i;
                    float v = (n < N && k < K) ? Bb[(size_t)k * ldb + n] : 0.0f;
                    s8[i] = f2bf(v);
                }
                *reinterpret_cast<bf16x8*>(&Bl[(q * 128 + c) * 8]) = s8;
            }
        }
        __syncthreads();
        // ---- compute ----
        bf16x8 af[4], bfr[4];
#pragma unroll
        for (int mi = 0; mi < 4; ++mi)
            af[mi] = *reinterpret_cast<const bf16x8*>(&Al[(quad * 128 + wm * 64 + mi * 16 + l15) * 8]);
#pragma unroll
        for (int ni = 0; ni < 4; ++ni)
            bfr[ni] = *reinterpret_cast<const bf16x8*>(&Bl[(quad * 128 + wn * 64 + ni * 16 + l15) * 8]);
#pragma unroll
        for (int mi = 0; mi < 4; ++mi)
#pragma unroll
            for (int ni = 0; ni < 4; ++ni)
                acc[mi][ni] = __builtin_amdgcn_mfma_f32_16x16x32_bf16(af[mi], bfr[ni], acc[mi][ni], 0, 0, 0);
        __syncthreads();
    }
    // ---- epilogue ----
    const float* rsp = rowscale ? rowscale + (size_t)z * sRS : nullptr;
#pragma unroll
    for (int mi = 0; mi < 4; ++mi) {
#pragma unroll
        for (int r = 0; r < 4; ++r) {
            int row = m0 + wm * 64 + mi * 16 + quad * 4 + r;
            if (row >= M) continue;
            float rsv = rsp ? rsp[row] : 1.0f;
#pragma unroll
            for (int ni = 0; ni < 4; ++ni) {
                int col = n0 + wn * 64 + ni * 16 + l15;
                if (col >= N) continue;
                float v = acc[mi][ni][r] * rsv;
                if (bias) v += bias[col];
                if (flags & GF_RELU) v = fmaxf(v, 0.0f);
                Cb[(size_t)row * ldc + col] = v;
            }
        }
    }
}

// ---------------------------------------------------------------------------
// MFMA attention: block = (b, h, 64-q-row tile). 4 waves, each owns 16 q rows.
// S kept in registers (25 x f32x4), softmax via shuffles, P -> LDS (A-frag
// layout), PV via MFMA with V streamed in 64-row chunks. LDS = 60 KB.
// ---------------------------------------------------------------------------
__global__ __launch_bounds__(256) void attn_mfma(
    const float* __restrict__ Qp, const float* __restrict__ Kp,
    const float* __restrict__ Vp, int ld,
    float* __restrict__ Out, int ldo)
{
    __shared__ short KP[26624];   // K (b-frag, [kq8][416][8]) then P (a-frag, [kq52][64][8])
    __shared__ short QV[4096];    // Q (a-frag, [kq8][64][8]) then V chunks ([kq8][64d][8])
    const int qt = blockIdx.x, h = blockIdx.y, b = blockIdx.z;
    const int tid = threadIdx.x;
    const int w = tid >> 6, lane = tid & 63;
    const int quad = lane >> 4, l15 = lane & 15;
    const size_t base = (size_t)b * NN * ld + h * HDD;

    // stage Q tile (rows qt*64..+63)
    for (int t = tid; t < 512; t += 256) {
        int m = t >> 3, kq = t & 7;
        int row = qt * 64 + m;
        bf16x8 s8;
        if (row < NN) {
            const float* src = Qp + base + (size_t)row * ld + kq * 8;
            float4 v0 = *(const float4*)src;
            float4 v1 = *(const float4*)(src + 4);
            s8[0] = f2bf(v0.x); s8[1] = f2bf(v0.y); s8[2] = f2bf(v0.z); s8[3] = f2bf(v0.w);
            s8[4] = f2bf(v1.x); s8[5] = f2bf(v1.y); s8[6] = f2bf(v1.z); s8[7] = f2bf(v1.w);
        } else { for (int j = 0; j < 8; ++j) s8[j] = 0; }
        *reinterpret_cast<bf16x8*>(&QV[(kq * 64 + m) * 8]) = s8;
    }
    // stage full K (416 padded rows)
    for (int t = tid; t < 3328; t += 256) {
        int n = t >> 3, kq = t & 7;
        bf16x8 s8;
        if (n < NN) {
            const float* src = Kp + base + (size_t)n * ld + kq * 8;
            float4 v0 = *(const float4*)src;
            float4 v1 = *(const float4*)(src + 4);
            s8[0] = f2bf(v0.x); s8[1] = f2bf(v0.y); s8[2] = f2bf(v0.z); s8[3] = f2bf(v0.w);
            s8[4] = f2bf(v1.x); s8[5] = f2bf(v1.y); s8[6] = f2bf(v1.z); s8[7] = f2bf(v1.w);
        } else { for (int j = 0; j < 8; ++j) s8[j] = 0; }
        *reinterpret_cast<bf16x8*>(&KP[(kq * 416 + n) * 8]) = s8;
    }
    __syncthreads();

    // phase 1: S = Q K^T (this wave's 16 q rows x 400 keys)
    bf16x8 aq0 = *reinterpret_cast<const bf16x8*>(&QV[(quad * 64 + w * 16 + l15) * 8]);
    bf16x8 aq1 = *reinterpret_cast<const bf16x8*>(&QV[((4 + quad) * 64 + w * 16 + l15) * 8]);
    f32x4 sacc[25];
#pragma unroll
    for (int nt = 0; nt < 25; ++nt) { sacc[nt][0] = 0; sacc[nt][1] = 0; sacc[nt][2] = 0; sacc[nt][3] = 0; }
#pragma unroll
    for (int nt = 0; nt < 25; ++nt) {
        bf16x8 b0 = *reinterpret_cast<const bf16x8*>(&KP[(quad * 416 + nt * 16 + l15) * 8]);
        bf16x8 b1 = *reinterpret_cast<const bf16x8*>(&KP[((4 + quad) * 416 + nt * 16 + l15) * 8]);
        sacc[nt] = __builtin_amdgcn_mfma_f32_16x16x32_bf16(aq0, b0, sacc[nt], 0, 0, 0);
        sacc[nt] = __builtin_amdgcn_mfma_f32_16x16x32_bf16(aq1, b1, sacc[nt], 0, 0, 0);
    }

    // softmax over 400 cols: lane holds rows (quad*4+r), col (nt*16 + l15)
    float mx[4] = {-3e38f, -3e38f, -3e38f, -3e38f}, sm[4] = {0, 0, 0, 0};
#pragma unroll
    for (int nt = 0; nt < 25; ++nt)
#pragma unroll
        for (int r = 0; r < 4; ++r) mx[r] = fmaxf(mx[r], sacc[nt][r]);
#pragma unroll
    for (int r = 0; r < 4; ++r) {
        mx[r] = fmaxf(mx[r], __shfl_xor(mx[r], 1));
        mx[r] = fmaxf(mx[r], __shfl_xor(mx[r], 2));
        mx[r] = fmaxf(mx[r], __shfl_xor(mx[r], 4));
        mx[r] = fmaxf(mx[r], __shfl_xor(mx[r], 8));
    }
#pragma unroll
    for (int nt = 0; nt < 25; ++nt)
#pragma unroll
        for (int r = 0; r < 4; ++r) {
            float e = __expf((sacc[nt][r] - mx[r]) * 0.125f);
            sacc[nt][r] = e;
            sm[r] += e;
        }
#pragma unroll
    for (int r = 0; r < 4; ++r) {
        sm[r] += __shfl_xor(sm[r], 1);
        sm[r] += __shfl_xor(sm[r], 2);
        sm[r] += __shfl_xor(sm[r], 4);
        sm[r] += __shfl_xor(sm[r], 8);
    }
    __syncthreads();  // all K reads done; KP now becomes P

    // write P (bf16) into A-frag layout [kq][64][8]; wave writes its own 16 rows
#pragma unroll
    for (int nt = 0; nt < 25; ++nt)
#pragma unroll
        for (int r = 0; r < 4; ++r) {
            int colk = nt * 16 + l15;
            KP[((colk >> 3) * 64 + w * 16 + quad * 4 + r) * 8 + (colk & 7)] = f2bf(sacc[nt][r]);
        }
    // zero pad tile (cols 400..415): kq planes 50,51
    for (int idx = tid; idx < 1024; idx += 256) KP[25600 + idx] = 0;

    // phase 2: O = P V, V streamed in 64-row chunks into QV
    f32x4 oacc[4];
#pragma unroll
    for (int dt = 0; dt < 4; ++dt) { oacc[dt][0] = 0; oacc[dt][1] = 0; oacc[dt][2] = 0; oacc[dt][3] = 0; }
    for (int kt = 0; kt < 13; ++kt) {
        if ((kt & 1) == 0) {
            __syncthreads();
            int v0r = (kt >> 1) * 64;
            for (int t = tid; t < 512; t += 256) {
                int d = t & 63, kq8 = t >> 6;
                bf16x8 s8;
#pragma unroll
                for (int i = 0; i < 8; ++i) {
                    int rrow = v0r + kq8 * 8 + i;
                    float v = (rrow < NN) ? Vp[base + (size_t)rrow * ld + d] : 0.0f;
                    s8[i] = f2bf(v);
                }
                *reinterpret_cast<bf16x8*>(&QV[(kq8 * 64 + d) * 8]) = s8;
            }
            __syncthreads();
        }
        bf16x8 pa = *reinterpret_cast<const bf16x8*>(&KP[((kt * 4 + quad) * 64 + w * 16 + l15) * 8]);
#pragma unroll
        for (int dt = 0; dt < 4; ++dt) {
            bf16x8 vb = *reinterpret_cast<const bf16x8*>(&QV[(((kt & 1) * 4 + quad) * 64 + dt * 16 + l15) * 8]);
            oacc[dt] = __builtin_amdgcn_mfma_f32_16x16x32_bf16(pa, vb, oacc[dt], 0, 0, 0);
        }
    }
#pragma unroll
    for (int r = 0; r < 4; ++r) {
        int row = qt * 64 + w * 16 + quad * 4 + r;
        if (row >= NN) continue;
        float inv = 1.0f / sm[r];
#pragma unroll
        for (int dt = 0; dt < 4; ++dt)
            Out[((size_t)b * NN + row) * ldo + h * HDD + dt * 16 + l15] = oacc[dt][r] * inv;
    }
}

// ---------------------------------------------------------------------------
// Column sums of sc -> dinv[b,j] = 1/sqrt(sum_i sc[b,i,j])
// ---------------------------------------------------------------------------
__global__ void colsum_dinv(const float* __restrict__ sc, float* __restrict__ dinv)
{
    int b = blockIdx.y;
    int j = blockIdx.x * 256 + threadIdx.x;
    if (j >= NN) return;
    const float* p = sc + (size_t)b * NN * NN + j;
    float s = 0.0f;
    for (int i = 0; i < NN; ++i) s += p[(size_t)i * NN];
    dinv[b * NN + j] = (s > 0.0f) ? 1.0f / sqrtf(s) : 0.0f;
}

// ---------------------------------------------------------------------------
// Fused residual + LayerNorm: y = LN(x + a) * g + b   (row len 256)
// ---------------------------------------------------------------------------
__global__ __launch_bounds__(256) void ln_res(
    const float* __restrict__ x, const float* __restrict__ a,
    const float* __restrict__ g, const float* __restrict__ bb,
    float* __restrict__ y, int rows)
{
    const int wave = threadIdx.x >> 6;
    const int lane = threadIdx.x & 63;
    const int row = blockIdx.x * 4 + wave;
    if (row >= rows) return;
    float4 xv = ((const float4*)(x + (size_t)row * DD))[lane];
    float4 av = ((const float4*)(a + (size_t)row * DD))[lane];
    float4 v;
    v.x = xv.x + av.x; v.y = xv.y + av.y; v.z = xv.z + av.z; v.w = xv.w + av.w;
    float s = v.x + v.y + v.z + v.w;
#pragma unroll
    for (int off = 32; off >= 1; off >>= 1) s += __shfl_xor(s, off);
    float mu = s * (1.0f / 256.0f);
    float d0 = v.x - mu, d1 = v.y - mu, d2 = v.z - mu, d3 = v.w - mu;
    float ss = d0 * d0 + d1 * d1 + d2 * d2 + d3 * d3;
#pragma unroll
    for (int off = 32; off >= 1; off >>= 1) ss += __shfl_xor(ss, off);
    float rstd = 1.0f / sqrtf(ss * (1.0f / 256.0f) + 1e-5f);
    float4 gv = ((const float4*)g)[lane];
    float4 bv = ((const float4*)bb)[lane];
    float4 out;
    out.x = d0 * rstd * gv.x + bv.x;
    out.y = d1 * rstd * gv.y + bv.y;
    out.z = d2 * rstd * gv.z + bv.z;
    out.w = d3 * rstd * gv.w + bv.w;
    ((float4*)(y + (size_t)row * DD))[lane] = out;
}

// ---------------------------------------------------------------------------
// Classifier split-K (fp32, exact): acc[b,o] += 0.5*(C1+C2)[b,k]*W1[o,k]
// ---------------------------------------------------------------------------
#define BM 64
#define BN 64
#define BK 16
#define CKC 512
__global__ __launch_bounds__(256) void cls_splitk(
    const float* __restrict__ C1, const float* __restrict__ C2,
    const float* __restrict__ W1, float* __restrict__ accum)
{
    __shared__ float As[BK][BM + 1];
    __shared__ float Ws[BK][BN + 1];
    const int n0 = blockIdx.x * 64;
    const int k0 = blockIdx.y * CKC;
    const int tid = threadIdx.x;
    const int ty = tid >> 4, tx = tid & 15;
    const int lk = tid & 15, lr = tid >> 4;
    float acc[4][4] = {};
    for (int kc = 0; kc < CKC; kc += BK) {
        int kb = k0 + kc;
#pragma unroll
        for (int i = 0; i < 4; ++i) {
            int r = lr + 16 * i;
            As[lk][r] = 0.5f * (C1[(size_t)r * 102400 + kb + lk] +
                                C2[(size_t)r * 102400 + kb + lk]);
            Ws[lk][r] = W1[(size_t)(n0 + r) * 102400 + kb + lk];
        }
        __syncthreads();
#pragma unroll
        for (int kk = 0; kk < BK; ++kk) {
            float a[4], b[4];
#pragma unroll
            for (int i = 0; i < 4; ++i) a[i] = As[kk][ty * 4 + i];
#pragma unroll
            for (int j = 0; j < 4; ++j) b[j] = Ws[kk][tx * 4 + j];
#pragma unroll
            for (int i = 0; i < 4; ++i)
#pragma unroll
                for (int j = 0; j < 4; ++j)
                    acc[i][j] = fmaf(a[i], b[j], acc[i][j]);
        }
        __syncthreads();
    }
#pragma unroll
    for (int i = 0; i < 4; ++i)
#pragma unroll
        for (int j = 0; j < 4; ++j)
            atomicAdd(&accum[(ty * 4 + i) * 128 + n0 + tx * 4 + j], acc[i][j]);
}

__global__ void zero_buf(float* p, int n)
{
    int i = blockIdx.x * 256 + threadIdx.x;
    if (i < n) p[i] = 0.0f;
}

__global__ void logits_final(
    const float* __restrict__ clsh, const float* __restrict__ b1,
    const float* __restrict__ w2, const float* __restrict__ b2,
    float* __restrict__ out)
{
    __shared__ float t[128];
    int b = blockIdx.x;
    int tid = threadIdx.x;
    t[tid] = fmaxf(clsh[b * 128 + tid] + b1[tid], 0.0f);
    __syncthreads();
    if (tid < 2) {
        float s = b2[tid];
        for (int o = 0; o < 128; ++o) s += t[o] * w2[tid * 128 + o];
        out[b * 2 + tid] = s;
    }
}

// ---------------------------------------------------------------------------
extern "C" void kernel_launch(void* const* d_in, const int* in_sizes, int n_in,
                              void* d_out, int out_size, void* d_ws, size_t ws_size,
                              hipStream_t stream)
{
    const float* fc        = (const float*)d_in[0];
    const float* sc        = (const float*)d_in[1];
    const float* proj_w    = (const float*)d_in[2];
    const float* proj_b    = (const float*)d_in[3];
    const float* enc_qkv_w = (const float*)d_in[4];
    const float* enc_qkv_b = (const float*)d_in[5];
    const float* enc_out_w = (const float*)d_in[6];
    const float* enc_out_b = (const float*)d_in[7];
    const float* enc_l1_w  = (const float*)d_in[8];
    const float* enc_l1_b  = (const float*)d_in[9];
    const float* enc_l2_w  = (const float*)d_in[10];
    const float* enc_l2_b  = (const float*)d_in[11];
    const float* enc_n1_g  = (const float*)d_in[12];
    const float* enc_n1_b  = (const float*)d_in[13];
    const float* enc_n2_g  = (const float*)d_in[14];
    const float* enc_n2_b  = (const float*)d_in[15];
    const float* gcn_w1    = (const float*)d_in[16];
    const float* gcn_b1    = (const float*)d_in[17];
    const float* gcn_w2    = (const float*)d_in[18];
    const float* gcn_b2    = (const float*)d_in[19];
    const float* ca1_qkv_w = (const float*)d_in[20];
    const float* ca1_qkv_b = (const float*)d_in[21];
    const float* ca1_out_w = (const float*)d_in[22];
    const float* ca1_out_b = (const float*)d_in[23];
    const float* ca1_n_g   = (const float*)d_in[24];
    const float* ca1_n_b   = (const float*)d_in[25];
    const float* ca2_qkv_w = (const float*)d_in[26];
    const float* ca2_qkv_b = (const float*)d_in[27];
    const float* ca2_out_w = (const float*)d_in[28];
    const float* ca2_out_b = (const float*)d_in[29];
    const float* ca2_n_g   = (const float*)d_in[30];
    const float* ca2_n_b   = (const float*)d_in[31];
    const float* cls_w1    = (const float*)d_in[32];
    const float* cls_b1    = (const float*)d_in[33];
    const float* cls_w2    = (const float*)d_in[34];
    const float* cls_b2    = (const float*)d_in[35];

    float* p = (float*)d_ws;
    float* bufH  = p; p += (size_t)MROWS * DD;       // Z_F working
    float* bufA  = p; p += (size_t)MROWS * DD;
    float* bufB  = p; p += (size_t)MROWS * DD;
    float* bufC  = p; p += (size_t)MROWS * DD;       // Z_F_cross
    float* bufZS = p; p += (size_t)MROWS * DD;       // Z_S / Z_S_cross
    float* bufBig = p; p += (size_t)MROWS * 1024;    // QKV (768) / FF (1024)
    float* dinv  = p; p += MROWS;
    float* clsh  = p; p += NB * 128;

    const int M = MROWS;
    dim3 blk(256);

    // ---- FC branch: input projection ----
    gemm_mfma<<<dim3(2, 200, 1), blk, 0, stream>>>(
        fc, NN, 0, proj_w, NN, 0, proj_b, nullptr, 0,
        bufH, DD, 0, M, DD, NN, 0);
    // ---- 2 encoder layers ----
    for (int l = 0; l < 2; ++l) {
        gemm_mfma<<<dim3(6, 200, 1), blk, 0, stream>>>(
            bufH, DD, 0, enc_qkv_w + (size_t)l * 768 * DD, DD, 0,
            enc_qkv_b + l * 768, nullptr, 0,
            bufBig, 768, 0, M, 768, DD, 0);
        attn_mfma<<<dim3(7, NHH, NB), blk, 0, stream>>>(
            bufBig, bufBig + 256, bufBig + 512, 768, bufA, DD);
        gemm_mfma<<<dim3(2, 200, 1), blk, 0, stream>>>(
            bufA, DD, 0, enc_out_w + (size_t)l * DD * DD, DD, 0,
            enc_out_b + l * DD, nullptr, 0,
            bufB, DD, 0, M, DD, DD, 0);
        ln_res<<<6400, blk, 0, stream>>>(bufH, bufB, enc_n1_g + l * DD,
                                         enc_n1_b + l * DD, bufH, M);
        gemm_mfma<<<dim3(8, 200, 1), blk, 0, stream>>>(
            bufH, DD, 0, enc_l1_w + (size_t)l * 1024 * DD, DD, 0,
            enc_l1_b + l * 1024, nullptr, 0,
            bufBig, 1024, 0, M, 1024, DD, GF_RELU);
        gemm_mfma<<<dim3(2, 200, 1), blk, 0, stream>>>(
            bufBig, 1024, 0, enc_l2_w + (size_t)l * DD * 1024, 1024, 0,
            enc_l2_b + l * DD, nullptr, 0,
            bufA, DD, 0, M, DD, 1024, 0);
        ln_res<<<6400, blk, 0, stream>>>(bufH, bufA, enc_n2_g + l * DD,
                                         enc_n2_b + l * DD, bufH, M);
    }
    // ---- GCN branch ----
    colsum_dinv<<<dim3(2, NB), blk, 0, stream>>>(sc, dinv);
    gemm_mfma<<<dim3(2, 200, 1), blk, 0, stream>>>(
        sc, NN, 0, gcn_w1, NN, 0, nullptr, dinv, 0,
        bufA, DD, 0, M, DD, NN, 0);
    gemm_mfma<<<dim3(2, 4, NB), blk, 0, stream>>>(
        sc, NN, (long long)NN * NN, bufA, DD, (long long)NN * DD,
        gcn_b1, dinv, NN,
        bufB, DD, (long long)NN * DD, NN, DD, NN, GF_RELU | GF_AT | GF_BT);
    gemm_mfma<<<dim3(2, 200, 1), blk, 0, stream>>>(
        bufB, DD, 0, gcn_w2, DD, 0, nullptr, dinv, 0,
        bufA, DD, 0, M, DD, DD, 0);
    gemm_mfma<<<dim3(2, 4, NB), blk, 0, stream>>>(
        sc, NN, (long long)NN * NN, bufA, DD, (long long)NN * DD,
        gcn_b2, dinv, NN,
        bufZS, DD, (long long)NN * DD, NN, DD, NN, GF_AT | GF_BT);

    // ---- Cross attention 1: Q = Z_F, KV = Z_S ----
    gemm_mfma<<<dim3(2, 200, 1), blk, 0, stream>>>(
        bufH, DD, 0, ca1_qkv_w, DD, 0, ca1_qkv_b, nullptr, 0,
        bufBig, 768, 0, M, 256, DD, 0);
    gemm_mfma<<<dim3(4, 200, 1), blk, 0, stream>>>(
        bufZS, DD, 0, ca1_qkv_w + 256 * DD, DD, 0, ca1_qkv_b + 256, nullptr, 0,
        bufBig + 256, 768, 0, M, 512, DD, 0);
    attn_mfma<<<dim3(7, NHH, NB), blk, 0, stream>>>(
        bufBig, bufBig + 256, bufBig + 512, 768, bufA, DD);
    gemm_mfma<<<dim3(2, 200, 1), blk, 0, stream>>>(
        bufA, DD, 0, ca1_out_w, DD, 0, ca1_out_b, nullptr, 0,
        bufB, DD, 0, M, DD, DD, 0);
    ln_res<<<6400, blk, 0, stream>>>(bufH, bufB, ca1_n_g, ca1_n_b, bufC, M);

    // ---- Cross attention 2: Q = Z_S, KV = Z_F ----
    gemm_mfma<<<dim3(2, 200, 1), blk, 0, stream>>>(
        bufZS, DD, 0, ca2_qkv_w, DD, 0, ca2_qkv_b, nullptr, 0,
        bufBig, 768, 0, M, 256, DD, 0);
    gemm_mfma<<<dim3(4, 200, 1), blk, 0, stream>>>(
        bufH, DD, 0, ca2_qkv_w + 256 * DD, DD, 0, ca2_qkv_b + 256, nullptr, 0,
        bufBig + 256, 768, 0, M, 512, DD, 0);
    attn_mfma<<<dim3(7, NHH, NB), blk, 0, stream>>>(
        bufBig, bufBig + 256, bufBig + 512, 768, bufA, DD);
    gemm_mfma<<<dim3(2, 200, 1), blk, 0, stream>>>(
        bufA, DD, 0, ca2_out_w, DD, 0, ca2_out_b, nullptr, 0,
        bufB, DD, 0, M, DD, DD, 0);
    ln_res<<<6400, blk, 0, stream>>>(bufZS, bufB, ca2_n_g, ca2_n_b, bufZS, M);

    // ---- Classifier (fp32 exact) ----
    zero_buf<<<(NB * 128 + 255) / 256, blk, 0, stream>>>(clsh, NB * 128);
    cls_splitk<<<dim3(2, 200), blk, 0, stream>>>(bufC, bufZS, cls_w1, clsh);
    logits_final<<<NB, 128, 0, stream>>>(clsh, cls_b1, cls_w2, cls_b2, (float*)d_out);
}

// Round 3
// 1441.761 us; speedup vs baseline: 3.8528x; 1.3371x over previous
//
#include <hip/hip_runtime.h>
#include <math.h>

// Problem constants
#define NB   64      // batch
#define NN   400     // nodes / seq len
#define DD   256     // model dim
#define NHH  4       // heads
#define HDD  64      // head dim
#define MROWS (NB*NN)   // 25600
#define KP416 416    // 400 padded to multiple of 32

typedef __attribute__((ext_vector_type(8))) short bf16x8;
typedef __attribute__((ext_vector_type(4))) float f32x4;

__device__ __forceinline__ short f2bf(float x) {
    union { float f; unsigned u; } v; v.f = x;
    return (short)((v.u + 0x7FFFu + ((v.u >> 16) & 1u)) >> 16);
}
__device__ __forceinline__ float bf2f(short s) {
    union { unsigned u; float f; } v; v.u = ((unsigned)(unsigned short)s) << 16;
    return v.f;
}
// async global->LDS, 16 bytes per lane; LDS dest = wave-uniform base + lane*16
__device__ __forceinline__ void gl_lds16(const void* g, void* l) {
    __builtin_amdgcn_global_load_lds(
        (const __attribute__((address_space(1))) unsigned*)g,
        (__attribute__((address_space(3))) unsigned*)l, 16, 0, 0);
}

// ---------------------------------------------------------------------------
// bf16 NT GEMM, 128x128 tile, BK=32, 4 waves x (4x4) 16x16x32 MFMAs.
// C[z][m][n] = act( sum_k A[z][m][k]*B[z][n][k] + bias[n] ), bf16 in/out.
// K must be a multiple of 32 (callers pre-pad with zeros).
// Cols in [N, Npad) are written as 0 (to zero-fill K-pad of downstream GEMMs).
// Staging reads may overrun rows past M/N into adjacent workspace (harmless).
// ---------------------------------------------------------------------------
__global__ __launch_bounds__(256) void gemm_bf16(
    const short* __restrict__ A, int lda, long long sA,
    const short* __restrict__ B, int ldb, long long sB,
    const float* __restrict__ bias,
    short* __restrict__ C, int ldc, long long sC,
    int M, int N, int Npad, int K, int relu)
{
    __shared__ short Al[4 * 128 * 8];
    __shared__ short Bl[4 * 128 * 8];
    const int tid = threadIdx.x;
    const int z = blockIdx.z;
    const int m0 = blockIdx.y * 128, n0 = blockIdx.x * 128;
    const short* Ab = A + (size_t)z * sA;
    const short* Bb = B + (size_t)z * sB;
    short* Cb = C + (size_t)z * sC;

    const int w = tid >> 6, lane = tid & 63;
    const int quad = lane >> 4, l15 = lane & 15;
    const int wm = w & 1, wn = w >> 1;

    f32x4 acc[4][4] = {};

    const int KT = K >> 5;
    for (int kt = 0; kt < KT; ++kt) {
        const int k0 = kt << 5;
        // stage A: wave w loads kq-plane w (chunks (q=w, m)), 2 halves of 64 rows
#pragma unroll
        for (int i = 0; i < 2; ++i)
            gl_lds16(Ab + (size_t)(m0 + i * 64 + lane) * lda + k0 + w * 8,
                     &Al[(w * 128 + i * 64) * 8]);
#pragma unroll
        for (int i = 0; i < 2; ++i)
            gl_lds16(Bb + (size_t)(n0 + i * 64 + lane) * ldb + k0 + w * 8,
                     &Bl[(w * 128 + i * 64) * 8]);
        __syncthreads();
        bf16x8 af[4], bfr[4];
#pragma unroll
        for (int mi = 0; mi < 4; ++mi)
            af[mi] = *reinterpret_cast<const bf16x8*>(&Al[(quad * 128 + wm * 64 + mi * 16 + l15) * 8]);
#pragma unroll
        for (int ni = 0; ni < 4; ++ni)
            bfr[ni] = *reinterpret_cast<const bf16x8*>(&Bl[(quad * 128 + wn * 64 + ni * 16 + l15) * 8]);
#pragma unroll
        for (int mi = 0; mi < 4; ++mi)
#pragma unroll
            for (int ni = 0; ni < 4; ++ni)
                acc[mi][ni] = __builtin_amdgcn_mfma_f32_16x16x32_bf16(af[mi], bfr[ni], acc[mi][ni], 0, 0, 0);
        __syncthreads();
    }
#pragma unroll
    for (int mi = 0; mi < 4; ++mi) {
#pragma unroll
        for (int r = 0; r < 4; ++r) {
            int row = m0 + wm * 64 + mi * 16 + quad * 4 + r;
            if (row >= M) continue;
#pragma unroll
            for (int ni = 0; ni < 4; ++ni) {
                int col = n0 + wn * 64 + ni * 16 + l15;
                if (col >= Npad) continue;
                float v = 0.0f;
                if (col < N) {
                    v = acc[mi][ni][r];
                    if (bias) v += bias[col];
                    if (relu) v = fmaxf(v, 0.0f);
                }
                Cb[(size_t)row * ldc + col] = f2bf(v);
            }
        }
    }
}

// ---------------------------------------------------------------------------
// MFMA attention (bf16 in/out): block = (q-tile of 64 rows, h, b).
// ---------------------------------------------------------------------------
__global__ __launch_bounds__(256) void attn_mfma(
    const short* __restrict__ Qp, const short* __restrict__ Kp,
    const short* __restrict__ Vp, int ld,
    short* __restrict__ Out, int ldo)
{
    __shared__ short KP[26624];   // K (b-frag, [kq8][416][8]) then P (a-frag, [kq52][64][8])
    __shared__ short QV[4096];    // Q (a-frag, [kq8][64][8]) then V chunks ([kq8][64d][8])
    const int qt = blockIdx.x, h = blockIdx.y, b = blockIdx.z;
    const int tid = threadIdx.x;
    const int w = tid >> 6, lane = tid & 63;
    const int quad = lane >> 4, l15 = lane & 15;
    const size_t base = (size_t)b * NN * ld + h * HDD;

    // stage Q (64 rows x 8 kq chunks) via global_load_lds
    for (int j = w; j < 8; j += 4)
        gl_lds16(Qp + base + (size_t)(qt * 64 + lane) * ld + j * 8, &QV[(j * 64) * 8]);
    // stage K (416 rows x 8 kq chunks = 3328 chunks); rows >=400 unused garbage
    for (int j = w; j < 52; j += 4) {
        int c = j * 64 + lane;
        int kq = c / 416, n = c - kq * 416;
        gl_lds16(Kp + base + (size_t)n * ld + kq * 8, &KP[(j * 64) * 8]);
    }
    __syncthreads();

    // phase 1: S = Q K^T (this wave's 16 q rows x 400 keys)
    bf16x8 aq0 = *reinterpret_cast<const bf16x8*>(&QV[(quad * 64 + w * 16 + l15) * 8]);
    bf16x8 aq1 = *reinterpret_cast<const bf16x8*>(&QV[((4 + quad) * 64 + w * 16 + l15) * 8]);
    f32x4 sacc[25];
#pragma unroll
    for (int nt = 0; nt < 25; ++nt) { sacc[nt][0] = 0; sacc[nt][1] = 0; sacc[nt][2] = 0; sacc[nt][3] = 0; }
#pragma unroll
    for (int nt = 0; nt < 25; ++nt) {
        bf16x8 b0 = *reinterpret_cast<const bf16x8*>(&KP[(quad * 416 + nt * 16 + l15) * 8]);
        bf16x8 b1 = *reinterpret_cast<const bf16x8*>(&KP[((4 + quad) * 416 + nt * 16 + l15) * 8]);
        sacc[nt] = __builtin_amdgcn_mfma_f32_16x16x32_bf16(aq0, b0, sacc[nt], 0, 0, 0);
        sacc[nt] = __builtin_amdgcn_mfma_f32_16x16x32_bf16(aq1, b1, sacc[nt], 0, 0, 0);
    }

    // softmax over 400 cols: lane holds rows (quad*4+r), col (nt*16 + l15)
    float mx[4] = {-3e38f, -3e38f, -3e38f, -3e38f}, sm[4] = {0, 0, 0, 0};
#pragma unroll
    for (int nt = 0; nt < 25; ++nt)
#pragma unroll
        for (int r = 0; r < 4; ++r) mx[r] = fmaxf(mx[r], sacc[nt][r]);
#pragma unroll
    for (int r = 0; r < 4; ++r) {
        mx[r] = fmaxf(mx[r], __shfl_xor(mx[r], 1));
        mx[r] = fmaxf(mx[r], __shfl_xor(mx[r], 2));
        mx[r] = fmaxf(mx[r], __shfl_xor(mx[r], 4));
        mx[r] = fmaxf(mx[r], __shfl_xor(mx[r], 8));
    }
#pragma unroll
    for (int nt = 0; nt < 25; ++nt)
#pragma unroll
        for (int r = 0; r < 4; ++r) {
            float e = __expf((sacc[nt][r] - mx[r]) * 0.125f);
            sacc[nt][r] = e;
            sm[r] += e;
        }
#pragma unroll
    for (int r = 0; r < 4; ++r) {
        sm[r] += __shfl_xor(sm[r], 1);
        sm[r] += __shfl_xor(sm[r], 2);
        sm[r] += __shfl_xor(sm[r], 4);
        sm[r] += __shfl_xor(sm[r], 8);
    }
    __syncthreads();  // all K reads done; KP now becomes P

    // write P (bf16) into A-frag layout [kq][64][8]
#pragma unroll
    for (int nt = 0; nt < 25; ++nt)
#pragma unroll
        for (int r = 0; r < 4; ++r) {
            int colk = nt * 16 + l15;
            KP[((colk >> 3) * 64 + w * 16 + quad * 4 + r) * 8 + (colk & 7)] = f2bf(sacc[nt][r]);
        }
    // zero pad planes (cols 400..415)
    for (int idx = tid; idx < 1024; idx += 256) KP[25600 + idx] = 0;

    // phase 2: O = P V, V streamed in 64-row chunks into QV
    f32x4 oacc[4];
#pragma unroll
    for (int dt = 0; dt < 4; ++dt) { oacc[dt][0] = 0; oacc[dt][1] = 0; oacc[dt][2] = 0; oacc[dt][3] = 0; }
    for (int kt = 0; kt < 13; ++kt) {
        if ((kt & 1) == 0) {
            __syncthreads();
            int v0r = (kt >> 1) * 64;
            for (int t = tid; t < 512; t += 256) {
                int d = t & 63, kq8 = t >> 6;
                bf16x8 s8;
#pragma unroll
                for (int i = 0; i < 8; ++i)
                    s8[i] = Vp[base + (size_t)(v0r + kq8 * 8 + i) * ld + d];  // P-pad zeros kill rows>=400
                *reinterpret_cast<bf16x8*>(&QV[(kq8 * 64 + d) * 8]) = s8;
            }
            __syncthreads();
        }
        bf16x8 pa = *reinterpret_cast<const bf16x8*>(&KP[((kt * 4 + quad) * 64 + w * 16 + l15) * 8]);
#pragma unroll
        for (int dt = 0; dt < 4; ++dt) {
            bf16x8 vb = *reinterpret_cast<const bf16x8*>(&QV[(((kt & 1) * 4 + quad) * 64 + dt * 16 + l15) * 8]);
            oacc[dt] = __builtin_amdgcn_mfma_f32_16x16x32_bf16(pa, vb, oacc[dt], 0, 0, 0);
        }
    }
#pragma unroll
    for (int r = 0; r < 4; ++r) {
        int row = qt * 64 + w * 16 + quad * 4 + r;
        if (row >= NN) continue;
        float inv = 1.0f / sm[r];
#pragma unroll
        for (int dt = 0; dt < 4; ++dt)
            Out[((size_t)b * NN + row) * ldo + h * HDD + dt * 16 + l15] = f2bf(oacc[dt][r] * inv);
    }
}

// ---------------------------------------------------------------------------
// fp32 -> bf16 with zero-padded columns: dst[r][c<K]=bf16(src[r][c]), else 0
// ---------------------------------------------------------------------------
__global__ void conv_bf16(const float* __restrict__ src, short* __restrict__ dst,
                          int rows, int K, int Kp)
{
    int idx = blockIdx.x * 256 + threadIdx.x;
    if (idx >= rows * Kp) return;
    int r = idx / Kp, c = idx - r * Kp;
    dst[idx] = (c < K) ? f2bf(src[(size_t)r * K + c]) : (short)0;
}

// ---------------------------------------------------------------------------
// Column sums of sc -> dinv[b,j] = 1/sqrt(sum_i sc[b,i,j])
// ---------------------------------------------------------------------------
__global__ void colsum_dinv(const float* __restrict__ sc, float* __restrict__ dinv)
{
    int b = blockIdx.y;
    int j = blockIdx.x * 256 + threadIdx.x;
    if (j >= NN) return;
    const float* p = sc + (size_t)b * NN * NN + j;
    float s = 0.0f;
    for (int i = 0; i < NN; ++i) s += p[(size_t)i * NN];
    dinv[b * NN + j] = (s > 0.0f) ? 1.0f / sqrtf(s) : 0.0f;
}

// ---------------------------------------------------------------------------
// sc prep: scb[b][i][j] = bf16(sc[b][i][j])  (j zero-padded to 416)
//          anT[b][j][i] = bf16(dinv_j * sc[b][i][j] * dinv_i)  (i padded 416)
// ---------------------------------------------------------------------------
__global__ __launch_bounds__(256) void sc_prep(
    const float* __restrict__ sc, const float* __restrict__ dinv,
    short* __restrict__ scb, short* __restrict__ anT)
{
    __shared__ float tile[64][65];
    const int b = blockIdx.z;
    const int i0 = blockIdx.y * 64, j0 = blockIdx.x * 64;
    const int tid = threadIdx.x;
    const float* sb = sc + (size_t)b * NN * NN;
    for (int e = tid; e < 4096; e += 256) {
        int r = e >> 6, c = e & 63;
        int i = i0 + r, j = j0 + c;
        tile[r][c] = (i < NN && j < NN) ? sb[(size_t)i * NN + j] : 0.0f;
    }
    __syncthreads();
    // plain copy (row-major, pad j)
    for (int e = tid; e < 4096; e += 256) {
        int r = e >> 6, c = e & 63;
        int i = i0 + r, j = j0 + c;
        if (i < NN && j < KP416)
            scb[((size_t)b * NN + i) * KP416 + j] = f2bf(tile[r][c]);
    }
    // scaled transpose (pad i)
    for (int e = tid; e < 4096; e += 256) {
        int c = e >> 6, r = e & 63;
        int i = i0 + r, j = j0 + c;
        if (j < NN && i < KP416) {
            float v = (i < NN) ? tile[r][c] * dinv[b * NN + i] * dinv[b * NN + j] : 0.0f;
            anT[((size_t)b * NN + j) * KP416 + i] = f2bf(v);
        }
    }
}

// ---------------------------------------------------------------------------
// Fused residual + LayerNorm (bf16 io): y = LN(x + a) * g + b, row len 256
// ---------------------------------------------------------------------------
__global__ __launch_bounds__(256) void ln_res(
    const short* __restrict__ x, const short* __restrict__ a,
    const float* __restrict__ g, const float* __restrict__ bb,
    short* __restrict__ y, int rows)
{
    const int wave = threadIdx.x >> 6;
    const int lane = threadIdx.x & 63;
    const int row = blockIdx.x * 4 + wave;
    if (row >= rows) return;
    short4 xv = ((const short4*)(x + (size_t)row * DD))[lane];
    short4 av = ((const short4*)(a + (size_t)row * DD))[lane];
    float v0 = bf2f(xv.x) + bf2f(av.x);
    float v1 = bf2f(xv.y) + bf2f(av.y);
    float v2 = bf2f(xv.z) + bf2f(av.z);
    float v3 = bf2f(xv.w) + bf2f(av.w);
    float s = v0 + v1 + v2 + v3;
#pragma unroll
    for (int off = 32; off >= 1; off >>= 1) s += __shfl_xor(s, off);
    float mu = s * (1.0f / 256.0f);
    float d0 = v0 - mu, d1 = v1 - mu, d2 = v2 - mu, d3 = v3 - mu;
    float ss = d0 * d0 + d1 * d1 + d2 * d2 + d3 * d3;
#pragma unroll
    for (int off = 32; off >= 1; off >>= 1) ss += __shfl_xor(ss, off);
    float rstd = 1.0f / sqrtf(ss * (1.0f / 256.0f) + 1e-5f);
    float4 gv = ((const float4*)g)[lane];
    float4 bv = ((const float4*)bb)[lane];
    short4 o;
    o.x = f2bf(d0 * rstd * gv.x + bv.x);
    o.y = f2bf(d1 * rstd * gv.y + bv.y);
    o.z = f2bf(d2 * rstd * gv.z + bv.z);
    o.w = f2bf(d3 * rstd * gv.w + bv.w);
    ((short4*)(y + (size_t)row * DD))[lane] = o;
}

// ---------------------------------------------------------------------------
// Classifier split-K (fp32 accum): acc[b,o] += 0.5*(C1+C2)[b,k]*W1[o,k]
// C1/C2 bf16, W1 fp32. grid (2, 200)
// ---------------------------------------------------------------------------
#define BM 64
#define BN 64
#define BK 16
#define CKC 512
__global__ __launch_bounds__(256) void cls_splitk(
    const short* __restrict__ C1, const short* __restrict__ C2,
    const float* __restrict__ W1, float* __restrict__ accum)
{
    __shared__ float As[BK][BM + 1];
    __shared__ float Ws[BK][BN + 1];
    const int n0 = blockIdx.x * 64;
    const int k0 = blockIdx.y * CKC;
    const int tid = threadIdx.x;
    const int ty = tid >> 4, tx = tid & 15;
    const int lk = tid & 15, lr = tid >> 4;
    float acc[4][4] = {};
    for (int kc = 0; kc < CKC; kc += BK) {
        int kb = k0 + kc;
#pragma unroll
        for (int i = 0; i < 4; ++i) {
            int r = lr + 16 * i;
            As[lk][r] = 0.5f * (bf2f(C1[(size_t)r * 102400 + kb + lk]) +
                                bf2f(C2[(size_t)r * 102400 + kb + lk]));
            Ws[lk][r] = W1[(size_t)(n0 + r) * 102400 + kb + lk];
        }
        __syncthreads();
#pragma unroll
        for (int kk = 0; kk < BK; ++kk) {
            float a[4], b[4];
#pragma unroll
            for (int i = 0; i < 4; ++i) a[i] = As[kk][ty * 4 + i];
#pragma unroll
            for (int j = 0; j < 4; ++j) b[j] = Ws[kk][tx * 4 + j];
#pragma unroll
            for (int i = 0; i < 4; ++i)
#pragma unroll
                for (int j = 0; j < 4; ++j)
                    acc[i][j] = fmaf(a[i], b[j], acc[i][j]);
        }
        __syncthreads();
    }
#pragma unroll
    for (int i = 0; i < 4; ++i)
#pragma unroll
        for (int j = 0; j < 4; ++j)
            atomicAdd(&accum[(ty * 4 + i) * 128 + n0 + tx * 4 + j], acc[i][j]);
}

__global__ void zero_buf(float* p, int n)
{
    int i = blockIdx.x * 256 + threadIdx.x;
    if (i < n) p[i] = 0.0f;
}

__global__ void logits_final(
    const float* __restrict__ clsh, const float* __restrict__ b1,
    const float* __restrict__ w2, const float* __restrict__ b2,
    float* __restrict__ out)
{
    __shared__ float t[128];
    int b = blockIdx.x;
    int tid = threadIdx.x;
    t[tid] = fmaxf(clsh[b * 128 + tid] + b1[tid], 0.0f);
    __syncthreads();
    if (tid < 2) {
        float s = b2[tid];
        for (int o = 0; o < 128; ++o) s += t[o] * w2[tid * 128 + o];
        out[b * 2 + tid] = s;
    }
}

// ---------------------------------------------------------------------------
extern "C" void kernel_launch(void* const* d_in, const int* in_sizes, int n_in,
                              void* d_out, int out_size, void* d_ws, size_t ws_size,
                              hipStream_t stream)
{
    const float* fc        = (const float*)d_in[0];
    const float* sc        = (const float*)d_in[1];
    const float* proj_w    = (const float*)d_in[2];
    const float* proj_b    = (const float*)d_in[3];
    const float* enc_qkv_w = (const float*)d_in[4];
    const float* enc_qkv_b = (const float*)d_in[5];
    const float* enc_out_w = (const float*)d_in[6];
    const float* enc_out_b = (const float*)d_in[7];
    const float* enc_l1_w  = (const float*)d_in[8];
    const float* enc_l1_b  = (const float*)d_in[9];
    const float* enc_l2_w  = (const float*)d_in[10];
    const float* enc_l2_b  = (const float*)d_in[11];
    const float* enc_n1_g  = (const float*)d_in[12];
    const float* enc_n1_b  = (const float*)d_in[13];
    const float* enc_n2_g  = (const float*)d_in[14];
    const float* enc_n2_b  = (const float*)d_in[15];
    const float* gcn_w1    = (const float*)d_in[16];
    const float* gcn_b1    = (const float*)d_in[17];
    const float* gcn_w2    = (const float*)d_in[18];
    const float* gcn_b2    = (const float*)d_in[19];
    const float* ca1_qkv_w = (const float*)d_in[20];
    const float* ca1_qkv_b = (const float*)d_in[21];
    const float* ca1_out_w = (const float*)d_in[22];
    const float* ca1_out_b = (const float*)d_in[23];
    const float* ca1_n_g   = (const float*)d_in[24];
    const float* ca1_n_b   = (const float*)d_in[25];
    const float* ca2_qkv_w = (const float*)d_in[26];
    const float* ca2_qkv_b = (const float*)d_in[27];
    const float* ca2_out_w = (const float*)d_in[28];
    const float* ca2_out_b = (const float*)d_in[29];
    const float* ca2_n_g   = (const float*)d_in[30];
    const float* ca2_n_b   = (const float*)d_in[31];
    const float* cls_w1    = (const float*)d_in[32];
    const float* cls_b1    = (const float*)d_in[33];
    const float* cls_w2    = (const float*)d_in[34];
    const float* cls_b2    = (const float*)d_in[35];

    char* wsb = (char*)d_ws;
    size_t off = 0;
    auto alloc = [&](size_t bytes) { char* r = wsb + off; off += (bytes + 255) & ~(size_t)255; return r; };
    short* bufBig = (short*)alloc((size_t)MROWS * 1024 * 2);
    short* fcb    = (short*)alloc((size_t)MROWS * KP416 * 2);
    short* scb    = (short*)alloc((size_t)NB * NN * KP416 * 2);
    short* anT    = (short*)alloc((size_t)NB * NN * KP416 * 2);
    short* h1     = (short*)alloc((size_t)NB * NN * DD * 2);
    short* XT1    = (short*)alloc((size_t)NB * DD * KP416 * 2);
    short* XT2    = (short*)alloc((size_t)NB * DD * KP416 * 2);
    short* bufH   = (short*)alloc((size_t)MROWS * DD * 2);
    short* bufA   = (short*)alloc((size_t)MROWS * DD * 2);
    short* bufB   = (short*)alloc((size_t)MROWS * DD * 2);
    short* bufC   = (short*)alloc((size_t)MROWS * DD * 2);
    short* bufZS  = (short*)alloc((size_t)MROWS * DD * 2);
    short* projwb = (short*)alloc((size_t)256 * KP416 * 2);
    short* qkvwb  = (short*)alloc((size_t)2 * 768 * 256 * 2);
    short* outwb  = (short*)alloc((size_t)2 * 256 * 256 * 2);
    short* l1wb   = (short*)alloc((size_t)2 * 1024 * 256 * 2);
    short* l2wb   = (short*)alloc((size_t)2 * 256 * 1024 * 2);
    short* gw1b   = (short*)alloc((size_t)256 * KP416 * 2);
    short* gw2b   = (short*)alloc((size_t)256 * 256 * 2);
    short* c1qb   = (short*)alloc((size_t)768 * 256 * 2);
    short* c1ob   = (short*)alloc((size_t)256 * 256 * 2);
    short* c2qb   = (short*)alloc((size_t)768 * 256 * 2);
    short* c2ob   = (short*)alloc((size_t)256 * 256 * 2);
    float* dinv   = (float*)alloc((size_t)MROWS * 4);
    float* clsh   = (float*)alloc((size_t)NB * 128 * 4);

    dim3 blk(256);
    auto cgrid = [](long long n) { return dim3((unsigned)((n + 255) / 256)); };

    // ---- weight / input conversions ----
    conv_bf16<<<cgrid((long long)MROWS * KP416), blk, 0, stream>>>(fc, fcb, MROWS, 400, KP416);
    conv_bf16<<<cgrid(256 * KP416), blk, 0, stream>>>(proj_w, projwb, 256, 400, KP416);
    conv_bf16<<<cgrid(1536 * 256), blk, 0, stream>>>(enc_qkv_w, qkvwb, 1536, 256, 256);
    conv_bf16<<<cgrid(512 * 256), blk, 0, stream>>>(enc_out_w, outwb, 512, 256, 256);
    conv_bf16<<<cgrid(2048 * 256), blk, 0, stream>>>(enc_l1_w, l1wb, 2048, 256, 256);
    conv_bf16<<<cgrid(512 * 1024), blk, 0, stream>>>(enc_l2_w, l2wb, 512, 1024, 1024);
    conv_bf16<<<cgrid(256 * KP416), blk, 0, stream>>>(gcn_w1, gw1b, 256, 400, KP416);
    conv_bf16<<<cgrid(256 * 256), blk, 0, stream>>>(gcn_w2, gw2b, 256, 256, 256);
    conv_bf16<<<cgrid(768 * 256), blk, 0, stream>>>(ca1_qkv_w, c1qb, 768, 256, 256);
    conv_bf16<<<cgrid(256 * 256), blk, 0, stream>>>(ca1_out_w, c1ob, 256, 256, 256);
    conv_bf16<<<cgrid(768 * 256), blk, 0, stream>>>(ca2_qkv_w, c2qb, 768, 256, 256);
    conv_bf16<<<cgrid(256 * 256), blk, 0, stream>>>(ca2_out_w, c2ob, 256, 256, 256);

    // ---- FC branch: input projection ----
    gemm_bf16<<<dim3(2, 200, 1), blk, 0, stream>>>(
        fcb, KP416, 0, projwb, KP416, 0, proj_b,
        bufH, DD, 0, MROWS, DD, DD, KP416, 0);
    // ---- 2 encoder layers ----
    for (int l = 0; l < 2; ++l) {
        gemm_bf16<<<dim3(6, 200, 1), blk, 0, stream>>>(
            bufH, DD, 0, qkvwb + (size_t)l * 768 * 256, 256, 0, enc_qkv_b + l * 768,
            bufBig, 768, 0, MROWS, 768, 768, 256, 0);
        attn_mfma<<<dim3(7, NHH, NB), blk, 0, stream>>>(
            bufBig, bufBig + 256, bufBig + 512, 768, bufA, DD);
        gemm_bf16<<<dim3(2, 200, 1), blk, 0, stream>>>(
            bufA, DD, 0, outwb + (size_t)l * 256 * 256, 256, 0, enc_out_b + l * 256,
            bufB, DD, 0, MROWS, DD, DD, 256, 0);
        ln_res<<<6400, blk, 0, stream>>>(bufH, bufB, enc_n1_g + l * DD,
                                         enc_n1_b + l * DD, bufH, MROWS);
        gemm_bf16<<<dim3(8, 200, 1), blk, 0, stream>>>(
            bufH, DD, 0, l1wb + (size_t)l * 1024 * 256, 256, 0, enc_l1_b + l * 1024,
            bufBig, 1024, 0, MROWS, 1024, 1024, 256, 1);
        gemm_bf16<<<dim3(2, 200, 1), blk, 0, stream>>>(
            bufBig, 1024, 0, l2wb + (size_t)l * 256 * 1024, 1024, 0, enc_l2_b + l * 256,
            bufA, DD, 0, MROWS, DD, DD, 1024, 0);
        ln_res<<<6400, blk, 0, stream>>>(bufH, bufA, enc_n2_g + l * DD,
                                         enc_n2_b + l * DD, bufH, MROWS);
    }
    // ---- GCN branch (all standard NT via precomputed transposes) ----
    colsum_dinv<<<dim3(2, NB), blk, 0, stream>>>(sc, dinv);
    sc_prep<<<dim3(7, 7, NB), blk, 0, stream>>>(sc, dinv, scb, anT);
    // XT1[b][d][i] = sum_j gcn_w1[d][j] * sc[b][i][j]
    gemm_bf16<<<dim3(4, 2, NB), blk, 0, stream>>>(
        gw1b, KP416, 0, scb, KP416, (long long)NN * KP416, nullptr,
        XT1, KP416, (long long)DD * KP416, DD, NN, KP416, KP416, 0);
    // h1[b][j][d] = relu(sum_i anT[b][j][i] * XT1[b][d][i] + b1)
    gemm_bf16<<<dim3(2, 4, NB), blk, 0, stream>>>(
        anT, KP416, (long long)NN * KP416, XT1, KP416, (long long)DD * KP416, gcn_b1,
        h1, DD, (long long)NN * DD, NN, DD, DD, KP416, 1);
    // XT2[b][e][i] = sum_d gcn_w2[e][d] * h1[b][i][d]
    gemm_bf16<<<dim3(4, 2, NB), blk, 0, stream>>>(
        gw2b, 256, 0, h1, DD, (long long)NN * DD, nullptr,
        XT2, KP416, (long long)DD * KP416, DD, NN, KP416, 256, 0);
    // Z_S[b][j][e] = sum_i anT[b][j][i] * XT2[b][e][i] + b2
    gemm_bf16<<<dim3(2, 4, NB), blk, 0, stream>>>(
        anT, KP416, (long long)NN * KP416, XT2, KP416, (long long)DD * KP416, gcn_b2,
        bufZS, DD, (long long)NN * DD, NN, DD, DD, KP416, 0);

    // ---- Cross attention 1: Q = Z_F, KV = Z_S ----
    gemm_bf16<<<dim3(2, 200, 1), blk, 0, stream>>>(
        bufH, DD, 0, c1qb, 256, 0, ca1_qkv_b,
        bufBig, 768, 0, MROWS, 256, 256, 256, 0);
    gemm_bf16<<<dim3(4, 200, 1), blk, 0, stream>>>(
        bufZS, DD, 0, c1qb + 256 * 256, 256, 0, ca1_qkv_b + 256,
        bufBig + 256, 768, 0, MROWS, 512, 512, 256, 0);
    attn_mfma<<<dim3(7, NHH, NB), blk, 0, stream>>>(
        bufBig, bufBig + 256, bufBig + 512, 768, bufA, DD);
    gemm_bf16<<<dim3(2, 200, 1), blk, 0, stream>>>(
        bufA, DD, 0, c1ob, 256, 0, ca1_out_b,
        bufB, DD, 0, MROWS, DD, DD, 256, 0);
    ln_res<<<6400, blk, 0, stream>>>(bufH, bufB, ca1_n_g, ca1_n_b, bufC, MROWS);

    // ---- Cross attention 2: Q = Z_S, KV = Z_F ----
    gemm_bf16<<<dim3(2, 200, 1), blk, 0, stream>>>(
        bufZS, DD, 0, c2qb, 256, 0, ca2_qkv_b,
        bufBig, 768, 0, MROWS, 256, 256, 256, 0);
    gemm_bf16<<<dim3(4, 200, 1), blk, 0, stream>>>(
        bufH, DD, 0, c2qb + 256 * 256, 256, 0, ca2_qkv_b + 256,
        bufBig + 256, 768, 0, MROWS, 512, 512, 256, 0);
    attn_mfma<<<dim3(7, NHH, NB), blk, 0, stream>>>(
        bufBig, bufBig + 256, bufBig + 512, 768, bufA, DD);
    gemm_bf16<<<dim3(2, 200, 1), blk, 0, stream>>>(
        bufA, DD, 0, c2ob, 256, 0, ca2_out_b,
        bufB, DD, 0, MROWS, DD, DD, 256, 0);
    ln_res<<<6400, blk, 0, stream>>>(bufZS, bufB, ca2_n_g, ca2_n_b, bufZS, MROWS);

    // ---- Classifier (fp32 accum) ----
    zero_buf<<<cgrid(NB * 128), blk, 0, stream>>>(clsh, NB * 128);
    cls_splitk<<<dim3(2, 200), blk, 0, stream>>>(bufC, bufZS, cls_w1, clsh);
    logits_final<<<NB, 128, 0, stream>>>(clsh, cls_b1, cls_w2, cls_b2, (float*)d_out);
}